// Round 6
// baseline (305.476 us; speedup 1.0000x reference)
//
#include <hip/hip_runtime.h>
#include <float.h>
#include <math.h>

#define N_PTS 8192
#define NB    256         // blocks (1 per CU)
#define NT    512         // 8 waves/block -> 2 waves/SIMD
#define QPB   32          // queries per block
#define QPT   8           // queries per thread (per ds_read)
#define NRG   128         // candidate ranges
#define RC    64          // candidates per range
#define STEPS 11          // STEPLIM + 1
#define TOLV  1e-4

#define PADSLOT(i) ((i) + ((i) >> 6))
#define SC_SZ (N_PTS + N_PTS/64)   // 8320 float4 slots = 133120 B

// ---- ws layout (bytes) ----
#define WS_P2F    0         // float4[8192]   = 131072
#define WS_TEMPPC 131072    // float [24576]  ->  229376
#define WS_BPA    229376    // double[256*16] ->  262144
#define WS_BPB    262144    // double[256*16] ->  294912
#define WS_ERRH   294912    // double[16]     ->  295040
#define WS_DONEH  295040    // int[16]

// ===========================================================================
// Kabsch via Jacobi eigendecomposition of H^T H (double, single thread).
// ===========================================================================
__device__ void kabsch3(const double H[3][3], const double c1[3], const double c2[3],
                        double R[3][3], double t[3]) {
    double A[3][3];
    for (int i = 0; i < 3; ++i)
        for (int j = 0; j < 3; ++j) {
            double sacc = 0.0;
            for (int k = 0; k < 3; ++k) sacc += H[k][i] * H[k][j];
            A[i][j] = sacc;
        }
    double V[3][3] = {{1,0,0},{0,1,0},{0,0,1}};
    for (int sweep = 0; sweep < 6; ++sweep) {
        const int PQ[3][2] = {{0,1},{0,2},{1,2}};
        for (int mm = 0; mm < 3; ++mm) {
            int p = PQ[mm][0], q = PQ[mm][1];
            double apq = A[p][q];
            if (fabs(apq) < 1e-300) continue;
            double app = A[p][p], aqq = A[q][q];
            double tau = (aqq - app) / (2.0 * apq);
            double tt = (tau >= 0.0) ? 1.0 / (tau + sqrt(1.0 + tau*tau))
                                     : 1.0 / (tau - sqrt(1.0 + tau*tau));
            double c = 1.0 / sqrt(1.0 + tt*tt), s = tt * c;
            A[p][p] = app - tt * apq;
            A[q][q] = aqq + tt * apq;
            A[p][q] = 0.0; A[q][p] = 0.0;
            int k = 3 - p - q;
            double akp = A[k][p], akq = A[k][q];
            A[k][p] = c*akp - s*akq; A[p][k] = A[k][p];
            A[k][q] = s*akp + c*akq; A[q][k] = A[k][q];
            for (int r = 0; r < 3; ++r) {
                double vp = V[r][p], vq = V[r][q];
                V[r][p] = c*vp - s*vq;
                V[r][q] = s*vp + c*vq;
            }
        }
    }
    double lam[3] = {A[0][0], A[1][1], A[2][2]};
    int ord[3] = {0,1,2};
    for (int i = 0; i < 2; ++i)
        for (int j = i+1; j < 3; ++j)
            if (lam[ord[j]] > lam[ord[i]]) { int tmp = ord[i]; ord[i] = ord[j]; ord[j] = tmp; }
    double v0[3] = {V[0][ord[0]], V[1][ord[0]], V[2][ord[0]]};
    double v1[3] = {V[0][ord[1]], V[1][ord[1]], V[2][ord[1]]};
    double v2[3] = {V[0][ord[2]], V[1][ord[2]], V[2][ord[2]]};

    double u0[3], u1[3], hv2[3];
    for (int i = 0; i < 3; ++i) u0[i] = H[i][0]*v0[0] + H[i][1]*v0[1] + H[i][2]*v0[2];
    double n0 = sqrt(u0[0]*u0[0] + u0[1]*u0[1] + u0[2]*u0[2]);
    n0 = fmax(n0, 1e-300);
    for (int i = 0; i < 3; ++i) u0[i] /= n0;

    for (int i = 0; i < 3; ++i) u1[i] = H[i][0]*v1[0] + H[i][1]*v1[1] + H[i][2]*v1[2];
    double d01 = u1[0]*u0[0] + u1[1]*u0[1] + u1[2]*u0[2];
    for (int i = 0; i < 3; ++i) u1[i] -= d01 * u0[i];
    double n1 = sqrt(u1[0]*u1[0] + u1[1]*u1[1] + u1[2]*u1[2]);
    n1 = fmax(n1, 1e-300);
    for (int i = 0; i < 3; ++i) u1[i] /= n1;

    double u2[3] = {u0[1]*u1[2] - u0[2]*u1[1],
                    u0[2]*u1[0] - u0[0]*u1[2],
                    u0[0]*u1[1] - u0[1]*u1[0]};
    for (int i = 0; i < 3; ++i) hv2[i] = H[i][0]*v2[0] + H[i][1]*v2[1] + H[i][2]*v2[2];
    if (hv2[0]*u2[0] + hv2[1]*u2[1] + hv2[2]*u2[2] < 0.0) {
        v2[0] = -v2[0]; v2[1] = -v2[1]; v2[2] = -v2[2];
    }
    double cx = v1[1]*v2[2] - v1[2]*v2[1];
    double cy = v1[2]*v2[0] - v1[0]*v2[2];
    double cz = v1[0]*v2[1] - v1[1]*v2[0];
    double detV = v0[0]*cx + v0[1]*cy + v0[2]*cz;
    double dsg = (detV < 0.0) ? -1.0 : 1.0;

    for (int i = 0; i < 3; ++i)
        for (int j = 0; j < 3; ++j)
            R[i][j] = v0[i]*u0[j] + v1[i]*u1[j] + dsg * v2[i]*u2[j];
    for (int i = 0; i < 3; ++i)
        t[i] = c2[i] - (R[i][0]*c1[0] + R[i][1]*c1[1] + R[i][2]*c1[2]);
}

__device__ __forceinline__ void build_H(const double s[16], double c1[3], double c2[3],
                                        double H[3][3]) {
    const double Nn = (double)N_PTS;
    c1[0] = s[1]/Nn; c1[1] = s[2]/Nn; c1[2] = s[3]/Nn;
    c2[0] = s[4]/Nn; c2[1] = s[5]/Nn; c2[2] = s[6]/Nn;
    for (int i = 0; i < 3; ++i)
        for (int j = 0; j < 3; ++j)
            H[i][j] = s[7 + 3*i + j] - Nn * c1[i] * c2[j];
}

// ===========================================================================
// One ICP iteration per dispatch (it = 0..STEPS).
// NN mapping: 4 query-groups (8 queries each) x 128 ranges (64 candidates).
// Each ds_read_b128 feeds 8 queries -> LDS ops cut 4x vs r5 (VALU-bound scan).
// ===========================================================================
__global__ __launch_bounds__(NT, 2) void icp_step(
    const float* __restrict__ p1, const float* __restrict__ p2,
    float4* __restrict__ p2f, float* __restrict__ temppc,
    const double* __restrict__ bp_prev, double* __restrict__ bp_cur,
    double* __restrict__ err_hist, int* __restrict__ done_hist, int it)
{
    __shared__ float4 sCand[SC_SZ];      // 133120 B
    __shared__ float4 sQ[QPB];
    __shared__ float  sWB[8][QPT];
    __shared__ int    sWI[8][QPT];
    __shared__ float  sRt[12];
    __shared__ int    sDone;
    const int tid = threadIdx.x, bid = blockIdx.x;

    const int latched = (it > 0) ? done_hist[it-1] : 0;
    const bool scan_possible = (it < STEPS) && !latched;

    // ---- candidate staging (linear, bank-padded; wave-contiguous writes) ----
    if (scan_possible) {
        if (it == 0) {
            #pragma unroll
            for (int k = 0; k < 16; ++k) {
                int i = tid + NT*k;
                float x = p2[3*i], y = p2[3*i+1], z = p2[3*i+2];
                sCand[PADSLOT(i)] = make_float4(x, y, z, x*x + y*y + z*z);
            }
        } else {
            #pragma unroll
            for (int k = 0; k < 16; ++k) {
                int i = tid + NT*k;
                sCand[PADSLOT(i)] = p2f[i];
            }
        }
    }

    // ---- gate + Kabsch of step it-1 ----
    int done = 0;
    if (it == 0) {
        __syncthreads();   // staging complete before p2f slice write
        if (bid == 0 && tid == 0) { err_hist[0] = __builtin_inf(); done_hist[0] = 0; }
        if (tid < QPB) {
            int i = bid*QPB + tid;
            p2f[i] = sCand[PADSLOT(i)];
        }
    } else if (latched) {
        done = 1;
        if (bid == 0 && tid == 0) { done_hist[it] = 1; err_hist[it] = err_hist[it-1]; }
    } else {
        if (tid < 64) {
            double sv[16];
            #pragma unroll
            for (int k = 0; k < 16; ++k) sv[k] = 0.0;
            #pragma unroll
            for (int jj = 0; jj < 4; ++jj) {
                const double* row = bp_prev + (tid + 64*jj)*16;
                #pragma unroll
                for (int k = 0; k < 16; ++k) sv[k] += row[k];
            }
            #pragma unroll
            for (int off = 1; off < 64; off <<= 1) {
                #pragma unroll
                for (int k = 0; k < 16; ++k) sv[k] += __shfl_xor(sv[k], off, 64);
            }
            if (tid == 0) {
                double errnew = sv[0] / (double)N_PTS;
                double err = err_hist[it-1];
                double rel = fabs((errnew - err) / err);   // nan when err=inf -> false
                int nd = (rel < TOLV) ? 1 : 0;
                if (bid == 0) { done_hist[it] = nd; err_hist[it] = nd ? err : errnew; }
                sDone = nd;
                if (!nd) {
                    double c1[3], c2[3], H[3][3], Rm[3][3], tv[3];
                    build_H(sv, c1, c2, H);
                    kabsch3(H, c1, c2, Rm, tv);
                    for (int i = 0; i < 3; ++i) {
                        sRt[3*i]   = (float)Rm[i][0];
                        sRt[3*i+1] = (float)Rm[i][1];
                        sRt[3*i+2] = (float)Rm[i][2];
                        sRt[9+i]   = (float)tv[i];
                    }
                }
            }
        }
        __syncthreads();   // also covers staging
        done = sDone;
    }

    if (done && it < STEPS) return;   // frozen: later gates latch via done_hist

    // ---- own query coords: load, (transform), store, share ----
    if (tid < QPB) {
        int q = bid*QPB + tid;
        float x, y, z;
        if (it == 0) {
            x = p1[3*q]; y = p1[3*q+1]; z = p1[3*q+2];
            temppc[3*q] = x; temppc[3*q+1] = y; temppc[3*q+2] = z;
        } else {
            x = temppc[3*q]; y = temppc[3*q+1]; z = temppc[3*q+2];
            if (!done) {
                float nx = fmaf(sRt[0], x, fmaf(sRt[1], y, fmaf(sRt[2], z, sRt[9])));
                float ny = fmaf(sRt[3], x, fmaf(sRt[4], y, fmaf(sRt[5], z, sRt[10])));
                float nz = fmaf(sRt[6], x, fmaf(sRt[7], y, fmaf(sRt[8], z, sRt[11])));
                x = nx; y = ny; z = nz;
                temppc[3*q] = x; temppc[3*q+1] = y; temppc[3*q+2] = z;
            }
        }
        sQ[tid] = make_float4(x, y, z, x*x + y*y + z*z);
    }
    __syncthreads();

    // ---- final-fit partials (a = p1, b = final coords) ----
    if (it == STEPS) {
        if (tid < 64) {
            double vals[16];
            if (tid < 32) {
                int q = bid*QPB + tid;
                float ax = p1[3*q], ay = p1[3*q+1], az = p1[3*q+2];
                float4 b4 = sQ[tid];
                vals[0] = 0.0;
                vals[1] = (double)ax;   vals[2] = (double)ay;   vals[3] = (double)az;
                vals[4] = (double)b4.x; vals[5] = (double)b4.y; vals[6] = (double)b4.z;
                vals[7]  = (double)ax*b4.x; vals[8]  = (double)ax*b4.y; vals[9]  = (double)ax*b4.z;
                vals[10] = (double)ay*b4.x; vals[11] = (double)ay*b4.y; vals[12] = (double)ay*b4.z;
                vals[13] = (double)az*b4.x; vals[14] = (double)az*b4.y; vals[15] = (double)az*b4.z;
            } else {
                #pragma unroll
                for (int k = 0; k < 16; ++k) vals[k] = 0.0;
            }
            #pragma unroll
            for (int off = 1; off < 32; off <<= 1) {
                #pragma unroll
                for (int k = 0; k < 16; ++k) vals[k] += __shfl_xor(vals[k], off, 64);
            }
            if (tid == 0) {
                double* d = bp_cur + bid*16;
                #pragma unroll
                for (int k = 0; k < 16; ++k) d[k] = vals[k];
            }
        }
        return;
    }

    // ---- NN scan: group g (8 queries) x range r (64 candidates) ----
    const int g = tid >> 7;        // 0..3
    const int r = tid & 127;       // 0..127
    float qx[QPT], qy[QPT], qz[QPT];
    #pragma unroll
    for (int k = 0; k < QPT; ++k) {
        float4 a = sQ[QPT*g + k];
        qx[k] = -2.f*a.x; qy[k] = -2.f*a.y; qz[k] = -2.f*a.z;
    }
    float best[QPT]; int bi[QPT];
    #pragma unroll
    for (int k = 0; k < QPT; ++k) { best[k] = FLT_MAX; bi[k] = 0; }

    const int sb = 65*r;           // PADSLOT(64*r) -> contiguous 64 slots
    const int gb = 64*r;

#define PROC8(SJ, JJ)                                                 \
    {                                                                 \
        _Pragma("unroll")                                             \
        for (int k = 0; k < QPT; ++k) {                               \
            float v = fmaf(qx[k], (SJ).x, (SJ).w);                    \
            v = fmaf(qy[k], (SJ).y, v);                               \
            v = fmaf(qz[k], (SJ).z, v);                               \
            if (v < best[k]) { best[k] = v; bi[k] = (JJ); }           \
        }                                                             \
    }

    float4 cur = sCand[sb];
    #pragma unroll 4
    for (int j = 0; j < RC - 1; ++j) {
        float4 nxt = sCand[sb + j + 1];
        PROC8(cur, gb + j);
        cur = nxt;
    }
    PROC8(cur, gb + RC - 1);
#undef PROC8

    // ---- combine: full-wave butterfly over 64 ranges (lex-min on val,idx) ----
    #pragma unroll
    for (int off = 1; off < 64; off <<= 1) {
        #pragma unroll
        for (int k = 0; k < QPT; ++k) {
            float ov = __shfl_xor(best[k], off, 64);
            int   oi = __shfl_xor(bi[k],  off, 64);
            if (ov < best[k] || (ov == best[k] && oi < bi[k])) { best[k] = ov; bi[k] = oi; }
        }
    }
    const int w = tid >> 6;        // wave id 0..7 (group g = w>>1)
    if ((tid & 63) == 0) {
        #pragma unroll
        for (int k = 0; k < QPT; ++k) { sWB[w][k] = best[k]; sWI[w][k] = bi[k]; }
    }
    __syncthreads();

    // ---- per-query finisher + block covariance reduce ----
    if (tid < 64) {
        double vals[16];
        if (tid < 32) {
            int q = tid;                 // query within block
            int gg = q >> 3, k = q & 7;
            float bv = sWB[2*gg][k];   int bix = sWI[2*gg][k];
            float ov = sWB[2*gg+1][k]; int oi  = sWI[2*gg+1][k];
            if (ov < bv || (ov == bv && oi < bix)) { bv = ov; bix = oi; }
            float4 a4 = sQ[q];
            float d2 = fmaxf(bv + a4.w, 0.0f);
            float dmin = sqrtf(d2);
            float4 b4 = p2f[bix];
            vals[0] = (double)dmin;
            vals[1] = (double)a4.x; vals[2] = (double)a4.y; vals[3] = (double)a4.z;
            vals[4] = (double)b4.x; vals[5] = (double)b4.y; vals[6] = (double)b4.z;
            vals[7]  = (double)a4.x*b4.x; vals[8]  = (double)a4.x*b4.y; vals[9]  = (double)a4.x*b4.z;
            vals[10] = (double)a4.y*b4.x; vals[11] = (double)a4.y*b4.y; vals[12] = (double)a4.y*b4.z;
            vals[13] = (double)a4.z*b4.x; vals[14] = (double)a4.z*b4.y; vals[15] = (double)a4.z*b4.z;
        } else {
            #pragma unroll
            for (int k = 0; k < 16; ++k) vals[k] = 0.0;
        }
        #pragma unroll
        for (int off = 1; off < 32; off <<= 1) {
            #pragma unroll
            for (int k = 0; k < 16; ++k) vals[k] += __shfl_xor(vals[k], off, 64);
        }
        if (tid == 0) {
            double* d = bp_cur + bid*16;
            #pragma unroll
            for (int k = 0; k < 16; ++k) d[k] = vals[k];
        }
    }
}

// ---------------------------------------------------------------------------
__global__ void icp_final(const double* __restrict__ bp, float* __restrict__ out) {
    int tid = threadIdx.x;
    double sv[16];
    #pragma unroll
    for (int k = 0; k < 16; ++k) sv[k] = 0.0;
    #pragma unroll
    for (int j = 0; j < 4; ++j) {
        const double* row = bp + (tid + 64*j)*16;
        #pragma unroll
        for (int k = 0; k < 16; ++k) sv[k] += row[k];
    }
    #pragma unroll
    for (int off = 1; off < 64; off <<= 1) {
        #pragma unroll
        for (int k = 0; k < 16; ++k) sv[k] += __shfl_xor(sv[k], off, 64);
    }
    if (tid == 0) {
        double c1[3], c2[3], H[3][3], Rm[3][3], tv[3];
        build_H(sv, c1, c2, H);
        kabsch3(H, c1, c2, Rm, tv);
        for (int i = 0; i < 3; ++i) {
            out[4*i + 0] = (float)Rm[i][0];
            out[4*i + 1] = (float)Rm[i][1];
            out[4*i + 2] = (float)Rm[i][2];
            out[4*i + 3] = (float)tv[i];
        }
    }
}

// ===========================================================================
extern "C" void kernel_launch(void* const* d_in, const int* in_sizes, int n_in,
                              void* d_out, int out_size, void* d_ws, size_t ws_size,
                              hipStream_t stream) {
    const float* p1 = (const float*)d_in[0];
    const float* p2 = (const float*)d_in[1];
    float* out = (float*)d_out;
    char* ws = (char*)d_ws;

    float4* p2f       = (float4*)(ws + WS_P2F);
    float*  temppc    = (float*) (ws + WS_TEMPPC);
    double* bpA       = (double*)(ws + WS_BPA);
    double* bpB       = (double*)(ws + WS_BPB);
    double* err_hist  = (double*)(ws + WS_ERRH);
    int*    done_hist = (int*)   (ws + WS_DONEH);

    for (int it = 0; it <= STEPS; ++it) {
        double* cur  = (it & 1) ? bpB : bpA;
        double* prev = (it & 1) ? bpA : bpB;
        icp_step<<<NB, NT, 0, stream>>>(p1, p2, p2f, temppc, prev, cur,
                                        err_hist, done_hist, it);
    }
    // STEPS=11 is odd -> last write went to bpB
    icp_final<<<1, 64, 0, stream>>>(bpB, out);
}